// Round 7
// baseline (1956.573 us; speedup 1.0000x reference)
//
#include <hip/hip_runtime.h>

#define D      128
#define NINIT  100000
#define LVLS   64
#define M      4096
#define NRULES 256
#define NTOT   (NINIT + LVLS * M)
#define NDERIV (LVLS * M)
#define NBLK   256
#define BLOCK  512
#define TILE   16
#define GRP    (NBLK / 8)

typedef __attribute__((ext_vector_type(8))) short short8;   // 8 bf16 = 4 VGPRs
typedef __attribute__((ext_vector_type(4))) float floatx4;  // MFMA accumulator

__device__ __forceinline__ unsigned short f2bf(float x) {  // RNE fp32->bf16
  unsigned u = __float_as_uint(x);
  u += 0x7fffu + ((u >> 16) & 1u);
  return (unsigned short)(u >> 16);
}

// ---------------------------------------------------------------------------
// ws layout (bytes):
//   4096*g (g=0..7)   : xcnt[g]   (barrier group counters, separate pages)
//   4096*(8+g)        : xgen[g]
//   4096*16           : gcnt; +256: ggen
//   4096*17           : sums[2] fp32
//   FLAG_OFF          : flags u32 [NDERIV]  (1 MB, ready flags)
//   ST_OFF            : store bf16 [NTOT][128]
//   SI_OFF            : sorted_idx int [LVLS][M]
//   RO_OFF            : rule_off int [LVLS][NRULES+1]
// ---------------------------------------------------------------------------
#define FLAG_OFF (4096 * 18)
#define ST_OFF   (FLAG_OFF + (size_t)NDERIV * 4)
#define SI_OFF   (ST_OFF + (size_t)NTOT * D * 2)
#define RO_OFF   (SI_OFF + (size_t)LVLS * M * 4)

// Hierarchical grid barrier (8 group pages -> 1 global line).
__device__ __forceinline__ void grid_sync(char* ws, unsigned target) {
  __syncthreads();
  if (threadIdx.x == 0) {
    const unsigned g = blockIdx.x & 7u;
    unsigned* xcnt = (unsigned*)(ws + 4096 * g);
    unsigned* xgen = (unsigned*)(ws + 4096 * (8 + g));
    unsigned* gcnt = (unsigned*)(ws + 4096 * 16);
    unsigned* ggen = (unsigned*)(ws + 4096 * 16 + 256);
    if (__hip_atomic_fetch_add(xcnt, 1u, __ATOMIC_ACQ_REL,
                               __HIP_MEMORY_SCOPE_AGENT) == GRP - 1) {
      if (__hip_atomic_fetch_add(gcnt, 1u, __ATOMIC_ACQ_REL,
                                 __HIP_MEMORY_SCOPE_AGENT) == 7) {
        __hip_atomic_store(gcnt, 0u, __ATOMIC_RELAXED, __HIP_MEMORY_SCOPE_AGENT);
        __hip_atomic_store(ggen, target, __ATOMIC_RELEASE, __HIP_MEMORY_SCOPE_AGENT);
      } else {
        while (__hip_atomic_load(ggen, __ATOMIC_RELAXED,
                                 __HIP_MEMORY_SCOPE_AGENT) < target)
          __builtin_amdgcn_s_sleep(2);
        __builtin_amdgcn_fence(__ATOMIC_ACQUIRE, "agent");
      }
      __hip_atomic_store(xcnt, 0u, __ATOMIC_RELAXED, __HIP_MEMORY_SCOPE_AGENT);
      __hip_atomic_store(xgen, target, __ATOMIC_RELEASE, __HIP_MEMORY_SCOPE_AGENT);
    } else {
      while (__hip_atomic_load(xgen, __ATOMIC_RELAXED,
                               __HIP_MEMORY_SCOPE_AGENT) < target)
        __builtin_amdgcn_s_sleep(8);
      __builtin_amdgcn_fence(__ATOMIC_ACQUIRE, "agent");
    }
  }
  __syncthreads();
}

__device__ __forceinline__ float softplusf(float x) {
  return fmaxf(x, 0.f) + log1pf(expf(-fabsf(x)));
}

__global__ __launch_bounds__(BLOCK) void fused_kernel(
    const float* __restrict__ thax_table, const float* __restrict__ sine_table,
    const float* __restrict__ rule_W, const float* __restrict__ rule_b,
    const float* __restrict__ eval_w, const float* __restrict__ eval_b,
    const float* __restrict__ pos_vals, const float* __restrict__ neg_vals,
    const int* __restrict__ init_thax, const int* __restrict__ init_sine,
    const int* __restrict__ parents, const int* __restrict__ rules,
    float* __restrict__ out, char* __restrict__ ws) {
  __shared__ __align__(16) unsigned short pe[TILE * 264];  // padded rows
  __shared__ int s_sort[2 * NRULES + 1];                   // sort scratch
  __shared__ int s_sid[TILE];
  __shared__ float sred[16];

  float* sums = (float*)(ws + 4096 * 17);
  unsigned* flags = (unsigned*)(ws + FLAG_OFF);
  unsigned short* store = (unsigned short*)(ws + ST_OFF);
  int* sorted_idx = (int*)(ws + SI_OFF);
  int* rule_off = (int*)(ws + RO_OFF);

  const int tid = threadIdx.x, b = blockIdx.x;  // b = this block's rule
  const int wave = tid >> 6, lane = tid & 63;
  const int col = (wave << 4) + (lane & 15);

  // ---- pre A: rule b's weights fp32 -> bf16 frags, pinned in VGPRs ----
  short8 bf[8];
  {
    const float* Wr = rule_W + (size_t)b * (2 * D * D);
#pragma unroll
    for (int ks = 0; ks < 8; ++ks) {
      int krow = ks * 32 + (lane >> 4) * 8;
      unsigned short v[8];
#pragma unroll
      for (int q = 0; q < 8; ++q) v[q] = f2bf(Wr[(size_t)(krow + q) * D + col]);
      union { unsigned u[4]; short8 s; } c;
      c.u[0] = (unsigned)v[0] | ((unsigned)v[1] << 16);
      c.u[1] = (unsigned)v[2] | ((unsigned)v[3] << 16);
      c.u[2] = (unsigned)v[4] | ((unsigned)v[5] << 16);
      c.u[3] = (unsigned)v[6] | ((unsigned)v[7] << 16);
      bf[ks] = c.s;
    }
  }
  const float bias = rule_b[b * D + col];

  // ---- pre B: counting-sort by rule (blocks 0..63 handle level=b) ----
  if (b < LVLS) {
    int* cnt = s_sort;            // 256
    int* base = s_sort + NRULES;  // 257
    const int* rl = rules + (size_t)b * M;
    if (tid < NRULES) cnt[tid] = 0;
    __syncthreads();
    for (int m = tid; m < M; m += BLOCK) atomicAdd(&cnt[rl[m]], 1);
    __syncthreads();
    if (tid == 0) {
      int run = 0;
      for (int q = 0; q < NRULES; ++q) { base[q] = run; run += cnt[q]; }
      base[NRULES] = run;
    }
    __syncthreads();
    if (tid <= NRULES) rule_off[(size_t)b * (NRULES + 1) + tid] = base[tid];
    if (tid < NRULES) cnt[tid] = base[tid];
    __syncthreads();
    for (int m = tid; m < M; m += BLOCK) {
      int p = atomicAdd(&cnt[rl[m]], 1);
      sorted_idx[(size_t)b * M + p] = m;
    }
  }

  // ---- pre C: init embeddings (grid-stride) ----
  for (int idx = b * BLOCK + tid; idx < NINIT * 16; idx += NBLK * BLOCK) {
    int node = idx >> 4, sg = idx & 15;
    const float4* t = (const float4*)(thax_table + (size_t)init_thax[node] * D) + sg * 2;
    const float4* s = (const float4*)(sine_table + (size_t)init_sine[node] * D) + sg * 2;
    float4 a0 = t[0], a1 = t[1], b0 = s[0], b1 = s[1];
    float v[8] = {a0.x + b0.x, a0.y + b0.y, a0.z + b0.z, a0.w + b0.w,
                  a1.x + b1.x, a1.y + b1.y, a1.z + b1.z, a1.w + b1.w};
    uint4 pk;
    pk.x = (unsigned)f2bf(v[0]) | ((unsigned)f2bf(v[1]) << 16);
    pk.y = (unsigned)f2bf(v[2]) | ((unsigned)f2bf(v[3]) << 16);
    pk.z = (unsigned)f2bf(v[4]) | ((unsigned)f2bf(v[5]) << 16);
    pk.w = (unsigned)f2bf(v[6]) | ((unsigned)f2bf(v[7]) << 16);
    *(uint4*)(store + (size_t)node * D + sg * 8) = pk;
  }

  // ---- pre D: pos/neg sums ----
  {
    float sp = 0.f, sn = 0.f;
    for (int i = b * BLOCK + tid; i < NTOT; i += NBLK * BLOCK) {
      sp += pos_vals[i];
      sn += neg_vals[i];
    }
    for (int m = 32; m; m >>= 1) {
      sp += __shfl_xor(sp, m, 64);
      sn += __shfl_xor(sn, m, 64);
    }
    if (lane == 0) { sred[wave * 2] = sp; sred[wave * 2 + 1] = sn; }
    __syncthreads();
    if (tid == 0) {
      float tp = 0.f, tn = 0.f;
      for (int w = 0; w < 8; ++w) { tp += sred[w * 2]; tn += sred[w * 2 + 1]; }
      atomicAdd(&sums[0], tp);
      atomicAdd(&sums[1], tn);
    }
  }

  grid_sync(ws, 1u);  // init rows + sort tables visible everywhere

  // ---- dataflow level loop: block b = rule b, weights already in VGPRs ----
  const int j = tid >> 5, seg = tid & 31;  // staging role: 1 uint4/thread
  const int* ro = rule_off;
  int noff = ro[b];
  int ncnt = ro[b + 1] - noff;

  for (int l = 0; l < LVLS; ++l) {
    const int off = noff, cnt = ncnt;
    if (l + 1 < LVLS) {  // prefetch next level's slice bounds
      noff = ro[(size_t)(l + 1) * (NRULES + 1) + b];
      ncnt = ro[(size_t)(l + 1) * (NRULES + 1) + b + 1] - noff;
    }
    const int n_base = NINIT + l * M;
    const int* sidx = sorted_idx + (size_t)l * M + off;
    const int* par_l = parents + (size_t)l * M * 2;

    for (int t0 = 0; t0 < cnt; t0 += TILE) {
      const int tile_n = min(TILE, cnt - t0);
      // stage: poll parent flag (acquire), then load row
      {
        int gj = t0 + j;
        if (gj > cnt - 1) gj = cnt - 1;
        int sid = sidx[gj];
        if (seg == 0) s_sid[j] = sid;
        int p = par_l[sid * 2 + (seg >> 4)];
        if (p >= NINIT) {
          unsigned* fl = flags + (p - NINIT);
          while (__hip_atomic_load(fl, __ATOMIC_ACQUIRE,
                                   __HIP_MEMORY_SCOPE_AGENT) == 0)
            __builtin_amdgcn_s_sleep(1);
        }
        uint4 d = *(const uint4*)(store + (size_t)p * D + (seg & 15) * 8);
        *(uint4*)(pe + j * 264 + seg * 8) = d;
      }
      __syncthreads();

      floatx4 acc = {0.f, 0.f, 0.f, 0.f};
#pragma unroll
      for (int ks = 0; ks < 8; ++ks) {
        short8 a = *(const short8*)(pe + (lane & 15) * 264 + ks * 32 +
                                    (lane >> 4) * 8);
        acc = __builtin_amdgcn_mfma_f32_16x16x32_bf16(a, bf[ks], acc, 0, 0, 0);
      }
#pragma unroll
      for (int reg = 0; reg < 4; ++reg) {
        int row = (lane >> 4) * 4 + reg;
        int g2 = t0 + row;
        if (g2 < cnt) {
          float v = acc[reg] + bias;
          store[(size_t)(n_base + s_sid[row]) * D + col] =
              f2bf(v > 0.f ? v : 0.f);
        }
      }
      __syncthreads();  // vmcnt(0) drain: rows in L2 before flags release
      if (tid < tile_n)
        __hip_atomic_store(flags + ((size_t)l * M + s_sid[tid]), 1u,
                           __ATOMIC_RELEASE, __HIP_MEMORY_SCOPE_AGENT);
    }
  }

  grid_sync(ws, 2u);  // all levels visible

  // ---- loss phase ----
  {
    float a_loss = 0.f, a_pos = 0.f, a_neg = 0.f;
    const float pw = sums[1] / sums[0];
    const float eb = eval_b[0];
    const float4* wv = (const float4*)eval_w;

    for (int node = b * BLOCK + tid; node < NTOT; node += NBLK * BLOCK) {
      const uint4* v = (const uint4*)(store + (size_t)node * D);
      float dot = 0.f;
#pragma unroll
      for (int k = 0; k < 16; ++k) {
        uint4 u = v[k];
        float4 w0 = wv[k * 2], w1 = wv[k * 2 + 1];
        dot += __uint_as_float(u.x << 16) * w0.x +
               __uint_as_float(u.x & 0xffff0000u) * w0.y +
               __uint_as_float(u.y << 16) * w0.z +
               __uint_as_float(u.y & 0xffff0000u) * w0.w +
               __uint_as_float(u.z << 16) * w1.x +
               __uint_as_float(u.z & 0xffff0000u) * w1.y +
               __uint_as_float(u.w << 16) * w1.z +
               __uint_as_float(u.w & 0xffff0000u) * w1.w;
      }
      float logit = dot + eb;
      float p = pos_vals[node], n = neg_vals[node];
      float tot = p + n, y = p / tot;
      a_loss += tot * (pw * y * softplusf(-logit) + (1.f - y) * softplusf(logit));
      if (logit >= 0.f) a_pos += p; else a_neg += n;
    }
    for (int m = 32; m; m >>= 1) {
      a_loss += __shfl_xor(a_loss, m, 64);
      a_pos  += __shfl_xor(a_pos,  m, 64);
      a_neg  += __shfl_xor(a_neg,  m, 64);
    }
    float* racc = (float*)s_sort;
    if (tid == 0) { racc[0] = 0.f; racc[1] = 0.f; racc[2] = 0.f; }
    __syncthreads();
    if (lane == 0) {
      atomicAdd(&racc[0], a_loss);
      atomicAdd(&racc[1], a_pos);
      atomicAdd(&racc[2], a_neg);
    }
    __syncthreads();
    if (tid == 0) {
      atomicAdd(&out[0], racc[0]);
      atomicAdd(&out[1], racc[1]);
      atomicAdd(&out[2], racc[2]);
    }
  }
}

extern "C" void kernel_launch(void* const* d_in, const int* in_sizes, int n_in,
                              void* d_out, int out_size, void* d_ws, size_t ws_size,
                              hipStream_t stream) {
  const float* thax_table = (const float*)d_in[0];
  const float* sine_table = (const float*)d_in[1];
  const float* rule_W     = (const float*)d_in[2];
  const float* rule_b     = (const float*)d_in[3];
  const float* eval_w     = (const float*)d_in[4];
  const float* eval_b     = (const float*)d_in[5];
  const float* pos_vals   = (const float*)d_in[6];
  const float* neg_vals   = (const float*)d_in[7];
  const int*   init_thax  = (const int*)d_in[8];
  const int*   init_sine  = (const int*)d_in[9];
  const int*   parents    = (const int*)d_in[10];
  const int*   rules      = (const int*)d_in[11];

  hipMemsetAsync(d_out, 0, 3 * sizeof(float), stream);
  // barrier pages + sums + ready flags
  hipMemsetAsync(d_ws, 0, FLAG_OFF + (size_t)NDERIV * 4, stream);

  fused_kernel<<<NBLK, BLOCK, 0, stream>>>(
      thax_table, sine_table, rule_W, rule_b, eval_w, eval_b,
      pos_vals, neg_vals, init_thax, init_sine, parents, rules,
      (float*)d_out, (char*)d_ws);
}

// Round 8
// 898.469 us; speedup vs baseline: 2.1777x; 2.1777x over previous
//
#include <hip/hip_runtime.h>

#define D      128
#define NINIT  100000
#define LVLS   64
#define M      4096
#define NRULES 256
#define NTOT   (NINIT + LVLS * M)

typedef __attribute__((ext_vector_type(8))) short short8;   // 8 bf16 = 4 VGPRs
typedef __attribute__((ext_vector_type(4))) float floatx4;  // MFMA accumulator

__device__ __forceinline__ unsigned short f2bf(float x) {  // RNE fp32->bf16
  unsigned u = __float_as_uint(x);
  u += 0x7fffu + ((u >> 16) & 1u);
  return (unsigned short)(u >> 16);
}

// ws layout: 0: sums[2] fp32 | 256: store bf16 [NTOT][128] | WF: Wfrag |
// SI: sorted_idx [LVLS][M] | RO: rule_off [LVLS][257]
#define ST_OFF 256
#define WF_OFF (ST_OFF + (size_t)NTOT * D * 2)
#define SI_OFF (WF_OFF + (size_t)NRULES * 2 * D * D * 2)
#define RO_OFF (SI_OFF + (size_t)LVLS * M * 4)

// One-time: rule_W fp32 -> frag-linear bf16.
// Frag element (ks, ct, lane, j) = W[ks*32+(lane>>4)*8+j][ct*16+(lane&15)]
// at Wfrag[r][((ks*8+ct)*64+lane)*8 + j].
__global__ __launch_bounds__(256) void wprep_kernel(
    const float* __restrict__ W, unsigned short* __restrict__ Wfrag) {
  const int r = blockIdx.x;
  const int wave = threadIdx.x >> 6, lane = threadIdx.x & 63;
  const float* Wr = W + (size_t)r * (2 * D * D);
  unsigned short* out = Wfrag + (size_t)r * (2 * D * D);
  for (int f = wave; f < 64; f += 4) {
    int ks = f >> 3, ct = f & 7;
    int krow = ks * 32 + (lane >> 4) * 8;
    int col = ct * 16 + (lane & 15);
    unsigned short v[8];
#pragma unroll
    for (int j = 0; j < 8; ++j) v[j] = f2bf(Wr[(size_t)(krow + j) * D + col]);
    uint4 pk;
    pk.x = (unsigned)v[0] | ((unsigned)v[1] << 16);
    pk.y = (unsigned)v[2] | ((unsigned)v[3] << 16);
    pk.z = (unsigned)v[4] | ((unsigned)v[5] << 16);
    pk.w = (unsigned)v[6] | ((unsigned)v[7] << 16);
    *(uint4*)(out + ((size_t)f * 64 + lane) * 8) = pk;
  }
}

// One-time: counting-sort nodes by rule per level; writes sorted_idx + rule_off.
__global__ __launch_bounds__(256) void sort_kernel(
    const int* __restrict__ rules, int* __restrict__ sorted_idx,
    int* __restrict__ rule_off) {
  __shared__ int cnt[NRULES];
  __shared__ int base[NRULES + 1];
  const int l = blockIdx.x, t = threadIdx.x;
  const int* rl = rules + (size_t)l * M;
  cnt[t] = 0;
  __syncthreads();
  for (int m = t; m < M; m += 256) atomicAdd(&cnt[rl[m]], 1);
  __syncthreads();
  if (t == 0) {
    int run = 0;
    for (int r = 0; r < NRULES; ++r) { base[r] = run; run += cnt[r]; }
    base[NRULES] = run;
  }
  __syncthreads();
  rule_off[(size_t)l * (NRULES + 1) + t] = base[t];
  if (t == 0) rule_off[(size_t)l * (NRULES + 1) + NRULES] = base[NRULES];
  cnt[t] = base[t];
  __syncthreads();
  for (int m = t; m < M; m += 256) {
    int p = atomicAdd(&cnt[rl[m]], 1);
    sorted_idx[(size_t)l * M + p] = m;
  }
}

__global__ __launch_bounds__(256) void init_kernel(
    const float* __restrict__ thax_table, const float* __restrict__ sine_table,
    const int* __restrict__ init_thax, const int* __restrict__ init_sine,
    unsigned short* __restrict__ store) {
  int idx = blockIdx.x * 256 + threadIdx.x;
  int node = idx >> 4, seg = idx & 15;
  if (node >= NINIT) return;
  const float4* t = (const float4*)(thax_table + (size_t)init_thax[node] * D) + seg * 2;
  const float4* s = (const float4*)(sine_table + (size_t)init_sine[node] * D) + seg * 2;
  float4 a0 = t[0], a1 = t[1], b0 = s[0], b1 = s[1];
  float v[8] = {a0.x + b0.x, a0.y + b0.y, a0.z + b0.z, a0.w + b0.w,
                a1.x + b1.x, a1.y + b1.y, a1.z + b1.z, a1.w + b1.w};
  uint4 pk;
  pk.x = (unsigned)f2bf(v[0]) | ((unsigned)f2bf(v[1]) << 16);
  pk.y = (unsigned)f2bf(v[2]) | ((unsigned)f2bf(v[3]) << 16);
  pk.z = (unsigned)f2bf(v[4]) | ((unsigned)f2bf(v[5]) << 16);
  pk.w = (unsigned)f2bf(v[6]) | ((unsigned)f2bf(v[7]) << 16);
  *(uint4*)(store + (size_t)node * D + seg * 8) = pk;
}

__global__ __launch_bounds__(256) void sum_kernel(
    const float* __restrict__ pos, const float* __restrict__ neg,
    float* __restrict__ sums) {
  float sp = 0.f, sn = 0.f;
  for (int i = blockIdx.x * 256 + threadIdx.x; i < NTOT; i += gridDim.x * 256) {
    sp += pos[i];
    sn += neg[i];
  }
  for (int m = 32; m; m >>= 1) {
    sp += __shfl_xor(sp, m, 64);
    sn += __shfl_xor(sn, m, 64);
  }
  if ((threadIdx.x & 63) == 0) {
    atomicAdd(&sums[0], sp);
    atomicAdd(&sums[1], sn);
  }
}

// Two levels per launch. Block b = rule b; B-frags pinned in VGPRs for both
// phases. Phase A: level l0 (parents all pre-launch -> visible). Phase B:
// level l0+1; parents in level l0 are RECOMPUTED locally (bit-identical to
// phase-A output), so no cross-block visibility is ever required.
__global__ __launch_bounds__(512) void pair_kernel(
    unsigned short* __restrict__ store, const int* __restrict__ parents,
    const int* __restrict__ rules, const int* __restrict__ sorted_idx,
    const int* __restrict__ rule_off, const unsigned short* __restrict__ Wfrag,
    const float* __restrict__ Bv, int l0) {
  __shared__ __align__(16) unsigned short pe[16 * 264];  // A-tile, padded rows
  __shared__ __align__(16) unsigned short rrow[264];     // recompute A-row
  __shared__ int s_sid[16];
  __shared__ int s_list[32];  // (j<<13)|(side<<12)|p_local
  __shared__ int s_nre;

  const int tid = threadIdx.x, b = blockIdx.x;
  const int wave = tid >> 6, lane = tid & 63;
  const int col = (wave << 4) + (lane & 15);
  const int j = tid >> 5, seg = tid & 31, side = seg >> 4, s16 = seg & 15;

  // pinned B-frags + bias for rule b
  short8 bf[8];
#pragma unroll
  for (int ks = 0; ks < 8; ++ks)
    bf[ks] = *(const short8*)(Wfrag + (size_t)b * (2 * D * D) +
                              (((size_t)ks * 8 + wave) * 64 + lane) * 8);
  const float bias = Bv[b * D + col];

  const int l1 = l0 + 1;
  const int baseA = NINIT + l0 * M;
  const int baseB = NINIT + l1 * M;

  // ---------------- phase A: level l0 ----------------
  {
    const int* ro = rule_off + (size_t)l0 * (NRULES + 1);
    const int off = ro[b], cnt = ro[b + 1] - off;
    const int* sidx = sorted_idx + (size_t)l0 * M + off;
    const int* par = parents + (size_t)l0 * M * 2;
    for (int t0 = 0; t0 < cnt; t0 += 16) {
      __syncthreads();
      {
        int gj = min(t0 + j, cnt - 1);
        int sid = sidx[gj];
        if (seg == 0) s_sid[j] = sid;
        int p = par[sid * 2 + side];  // p < baseA: visible since launch
        uint4 d = *(const uint4*)(store + (size_t)p * D + s16 * 8);
        *(uint4*)(pe + j * 264 + seg * 8) = d;
      }
      __syncthreads();
      floatx4 acc = {0.f, 0.f, 0.f, 0.f};
#pragma unroll
      for (int ks = 0; ks < 8; ++ks) {
        short8 a = *(const short8*)(pe + (lane & 15) * 264 + ks * 32 +
                                    (lane >> 4) * 8);
        acc = __builtin_amdgcn_mfma_f32_16x16x32_bf16(a, bf[ks], acc, 0, 0, 0);
      }
#pragma unroll
      for (int reg = 0; reg < 4; ++reg) {
        int row = (lane >> 4) * 4 + reg;
        if (t0 + row < cnt) {
          float v = acc[reg] + bias;
          store[(size_t)(baseA + s_sid[row]) * D + col] = f2bf(v > 0.f ? v : 0.f);
        }
      }
    }
  }

  // ---------------- phase B: level l0+1 ----------------
  if (l1 < LVLS) {
    const int* ro = rule_off + (size_t)l1 * (NRULES + 1);
    const int off = ro[b], cnt = ro[b + 1] - off;
    const int* sidx = sorted_idx + (size_t)l1 * M + off;
    const int* par = parents + (size_t)l1 * M * 2;
    const int* parA = parents + (size_t)l0 * M * 2;
    for (int t0 = 0; t0 < cnt; t0 += 16) {
      __syncthreads();
      if (tid == 0) s_nre = 0;
      __syncthreads();
      {
        int gj = min(t0 + j, cnt - 1);
        int sid = sidx[gj];
        if (seg == 0) s_sid[j] = sid;
        int p = par[sid * 2 + side];
        if (p < baseA) {  // pre-launch: read row
          uint4 d = *(const uint4*)(store + (size_t)p * D + s16 * 8);
          *(uint4*)(pe + j * 264 + seg * 8) = d;
        } else if (s16 == 0) {  // level-l0 parent: defer to local recompute
          int e = atomicAdd(&s_nre, 1);
          s_list[e] = (j << 13) | (side << 12) | (p - baseA);
        }
      }
      __syncthreads();
      const int nre = s_nre;
      for (int e = 0; e < nre; ++e) {
        int ent = s_list[e];
        int ej = ent >> 13, eside = (ent >> 12) & 1, pl = ent & 0xfff;
        int r2 = rules[(size_t)l0 * M + pl];
        // stage p's parent-concat row (grandparents: all pre-launch)
        if (tid < 32) {
          int gp = parA[pl * 2 + (tid >> 4)];
          uint4 d = *(const uint4*)(store + (size_t)gp * D + (tid & 15) * 8);
          *(uint4*)(rrow + tid * 8) = d;
        }
        short8 b2[8];
#pragma unroll
        for (int ks = 0; ks < 8; ++ks)
          b2[ks] = *(const short8*)(Wfrag + (size_t)r2 * (2 * D * D) +
                                    (((size_t)ks * 8 + wave) * 64 + lane) * 8);
        const float bias2 = Bv[r2 * D + col];
        __syncthreads();  // rrow staged
        floatx4 acc2 = {0.f, 0.f, 0.f, 0.f};
#pragma unroll
        for (int ks = 0; ks < 8; ++ks) {
          // all lanes read the same A-row -> every output row equals row p
          short8 a2 = *(const short8*)(rrow + ks * 32 + (lane >> 4) * 8);
          acc2 = __builtin_amdgcn_mfma_f32_16x16x32_bf16(a2, b2[ks], acc2, 0, 0, 0);
        }
        if (lane < 16) {  // row 0 writers: 8 waves x 16 lanes = 128 cols
          float v = acc2[0] + bias2;
          pe[ej * 264 + eside * 128 + col] = f2bf(v > 0.f ? v : 0.f);
        }
        __syncthreads();  // pe write visible; rrow reusable
      }
      floatx4 acc = {0.f, 0.f, 0.f, 0.f};
#pragma unroll
      for (int ks = 0; ks < 8; ++ks) {
        short8 a = *(const short8*)(pe + (lane & 15) * 264 + ks * 32 +
                                    (lane >> 4) * 8);
        acc = __builtin_amdgcn_mfma_f32_16x16x32_bf16(a, bf[ks], acc, 0, 0, 0);
      }
#pragma unroll
      for (int reg = 0; reg < 4; ++reg) {
        int row = (lane >> 4) * 4 + reg;
        if (t0 + row < cnt) {
          float v = acc[reg] + bias;
          store[(size_t)(baseB + s_sid[row]) * D + col] = f2bf(v > 0.f ? v : 0.f);
        }
      }
    }
  }
}

__device__ __forceinline__ float softplusf(float x) {
  return fmaxf(x, 0.f) + log1pf(expf(-fabsf(x)));
}

__global__ __launch_bounds__(1024) void loss_kernel(
    const unsigned short* __restrict__ store, const float* __restrict__ eval_w,
    const float* __restrict__ eval_b, const float* __restrict__ pos,
    const float* __restrict__ neg, const float* __restrict__ sums,
    float* __restrict__ out) {
  float a_loss = 0.f, a_pos = 0.f, a_neg = 0.f;
  const float pw = sums[1] / sums[0];
  const float eb = eval_b[0];
  const float4* wv = (const float4*)eval_w;

  for (int node = blockIdx.x * 1024 + threadIdx.x; node < NTOT;
       node += gridDim.x * 1024) {
    const uint4* v = (const uint4*)(store + (size_t)node * D);
    float dot = 0.f;
#pragma unroll
    for (int k = 0; k < 16; ++k) {
      uint4 u = v[k];
      float4 w0 = wv[k * 2], w1 = wv[k * 2 + 1];
      dot += __uint_as_float(u.x << 16) * w0.x +
             __uint_as_float(u.x & 0xffff0000u) * w0.y +
             __uint_as_float(u.y << 16) * w0.z +
             __uint_as_float(u.y & 0xffff0000u) * w0.w +
             __uint_as_float(u.z << 16) * w1.x +
             __uint_as_float(u.z & 0xffff0000u) * w1.y +
             __uint_as_float(u.w << 16) * w1.z +
             __uint_as_float(u.w & 0xffff0000u) * w1.w;
    }
    float logit = dot + eb;
    float p = pos[node], n = neg[node];
    float tot = p + n, y = p / tot;
    a_loss += tot * (pw * y * softplusf(-logit) + (1.f - y) * softplusf(logit));
    if (logit >= 0.f) a_pos += p; else a_neg += n;
  }

  for (int m = 32; m; m >>= 1) {
    a_loss += __shfl_xor(a_loss, m, 64);
    a_pos  += __shfl_xor(a_pos,  m, 64);
    a_neg  += __shfl_xor(a_neg,  m, 64);
  }
  __shared__ float racc[3];
  if (threadIdx.x == 0) { racc[0] = 0.f; racc[1] = 0.f; racc[2] = 0.f; }
  __syncthreads();
  if ((threadIdx.x & 63) == 0) {
    atomicAdd(&racc[0], a_loss);
    atomicAdd(&racc[1], a_pos);
    atomicAdd(&racc[2], a_neg);
  }
  __syncthreads();
  if (threadIdx.x == 0) {
    atomicAdd(&out[0], racc[0]);
    atomicAdd(&out[1], racc[1]);
    atomicAdd(&out[2], racc[2]);
  }
}

extern "C" void kernel_launch(void* const* d_in, const int* in_sizes, int n_in,
                              void* d_out, int out_size, void* d_ws, size_t ws_size,
                              hipStream_t stream) {
  const float* thax_table = (const float*)d_in[0];
  const float* sine_table = (const float*)d_in[1];
  const float* rule_W     = (const float*)d_in[2];
  const float* rule_b     = (const float*)d_in[3];
  const float* eval_w     = (const float*)d_in[4];
  const float* eval_b     = (const float*)d_in[5];
  const float* pos_vals   = (const float*)d_in[6];
  const float* neg_vals   = (const float*)d_in[7];
  const int*   init_thax  = (const int*)d_in[8];
  const int*   init_sine  = (const int*)d_in[9];
  const int*   parents    = (const int*)d_in[10];
  const int*   rules      = (const int*)d_in[11];

  float* out = (float*)d_out;
  char* ws = (char*)d_ws;
  float* sums = (float*)ws;
  unsigned short* store = (unsigned short*)(ws + ST_OFF);
  unsigned short* Wfrag = (unsigned short*)(ws + WF_OFF);
  int* sorted_idx = (int*)(ws + SI_OFF);
  int* rule_off   = (int*)(ws + RO_OFF);

  hipMemsetAsync(d_out, 0, 3 * sizeof(float), stream);
  hipMemsetAsync(d_ws, 0, 2 * sizeof(float), stream);

  wprep_kernel<<<NRULES, 256, 0, stream>>>(rule_W, Wfrag);
  sort_kernel<<<LVLS, 256, 0, stream>>>(rules, sorted_idx, rule_off);
  init_kernel<<<(NINIT * 16 + 255) / 256, 256, 0, stream>>>(
      thax_table, sine_table, init_thax, init_sine, store);
  sum_kernel<<<256, 256, 0, stream>>>(pos_vals, neg_vals, sums);

  for (int l = 0; l < LVLS; l += 2) {
    pair_kernel<<<NRULES, 512, 0, stream>>>(
        store, parents, rules, sorted_idx, rule_off, Wfrag, rule_b, l);
  }

  loss_kernel<<<512, 1024, 0, stream>>>(
      store, eval_w, eval_b, pos_vals, neg_vals, sums, out);
}